// Round 11
// baseline (142.317 us; speedup 1.0000x reference)
//
#include <hip/hip_runtime.h>
#include <hip/hip_bf16.h>

#define NROWS 4096
#define DIM   1024           // K elements; 1024 B/row in fp8
#define BT    256            // tile edge (256x256 per block)
#define BK    128            // K-step (128 B in fp8)
#define NKT   (DIM / BK)     // 8 K-steps
#define NTB   (NROWS / BT)   // 16 tile-blocks per edge
#define TEMP_INV 10.0f
#define INV_S2 0.00390625f   // 1/256 (fp8 stored as 16*x)
#define SCALE1 0x7F7F7F7F    // E8M0 1.0 in all 4 bytes

typedef float f32x16 __attribute__((ext_vector_type(16)));
typedef int   i32x8  __attribute__((ext_vector_type(8)));
typedef int   i32x4  __attribute__((ext_vector_type(4)));

__device__ __forceinline__ void gload16(const void* g, void* l) {
    __builtin_amdgcn_global_load_lds(
        (const __attribute__((address_space(1))) void*)g,
        (__attribute__((address_space(3))) void*)l, 16, 0, 0);
}

// Stage one 256x128 fp8 K-tile (32 KB) into LDS, 4 x gload16 per thread
// (512 thr).  Byte-identical to R9's proven staging (2.6 us/64KB-step at the
// aggregate ceiling).  Linear LDS dest (m104); granule swizzle kg = (p&7)^(r&7)
// pre-applied on the global source (rule 21).
__device__ __forceinline__ void stage_tile(const unsigned char* __restrict__ src,
                                           unsigned char* lds, int tid) {
    #pragma unroll
    for (int c = 0; c < 4; ++c) {
        const int p  = c * 512 + tid;        // granule 0..2047
        const int r  = p >> 3;               // tile row 0..255
        const int kg = (p & 7) ^ (r & 7);    // logical k-granule held at p
        gload16(src + (size_t)r * DIM + kg * 16, lds + p * 16);
    }
}

// Row-normalize fp32 -> fp8 e4m3 scaled by 16; zeroes partial accumulators.
__global__ __launch_bounds__(256) void normalize_k(const float* __restrict__ pred,
                                                   unsigned char* __restrict__ xn,
                                                   float* __restrict__ posw,
                                                   float* __restrict__ denw) {
    const int row = blockIdx.x;
    const int tid = threadIdx.x;
    const float4 v = reinterpret_cast<const float4*>(pred + (size_t)row * DIM)[tid];
    float ss = v.x * v.x + v.y * v.y + v.z * v.z + v.w * v.w;
    #pragma unroll
    for (int off = 32; off; off >>= 1) ss += __shfl_xor(ss, off, 64);
    __shared__ float red[4];
    if ((tid & 63) == 0) red[tid >> 6] = ss;
    __syncthreads();
    const float tot = red[0] + red[1] + red[2] + red[3];
    const float scale = 16.0f / fmaxf(sqrtf(tot), 1e-8f);
    int pk = __builtin_amdgcn_cvt_pk_fp8_f32(v.x * scale, v.y * scale, 0, false);
    pk     = __builtin_amdgcn_cvt_pk_fp8_f32(v.z * scale, v.w * scale, pk, true);
    reinterpret_cast<int*>(xn)[row * (DIM / 4) + tid] = pk;
    if (tid == 0) { posw[row] = 0.0f; denw[row] = 0.0f; }
}

#define BAR asm volatile("s_barrier" ::: "memory")

// Fused Gram-GEMM + contrastive epilogue.  Full 16x16 grid (256 blocks,
// 1/CU), 8 waves (2M x 4N), per-wave output 128x64 via 4x2 blocks of
// 32x32x64 MX-scaled fp8 MFMA (scale = 1.0).  R4/R9's proven counted-vmcnt
// staging (64 KB/step, depth-2, vmcnt(8)); fragments are 2 x ds_read_b128
// per 32B operand (2-way bank aliasing = free).
__global__ __launch_bounds__(512, 2) void fused_gram(
        const unsigned char* __restrict__ xn, const int* __restrict__ tgt,
        float* __restrict__ posw, float* __restrict__ denw) {
    __shared__ unsigned char As[2][BT * BK];   // 2 x 32 KB
    __shared__ unsigned char Bs[2][BT * BK];   // 2 x 32 KB  (128 KB total)

    const int bi = blockIdx.x >> 4;
    const int bj = blockIdx.x & 15;
    const int rowbase = bi * BT;
    const int colbase = bj * BT;

    const int tid = threadIdx.x;
    const int w   = tid >> 6;
    const int l   = tid & 63;
    const int wr  = w >> 2;      // 0..1  (row half: 128 rows)
    const int wc  = w & 3;       // 0..3  (col quarter: 64 cols)
    const int l31 = l & 31;
    const int h   = l >> 5;      // k-half selector
    const int swz = l & 7;

    const unsigned char* arow = xn + (size_t)rowbase * DIM;
    const unsigned char* bcol = xn + (size_t)colbase * DIM;

    // Per-lane LDS byte offsets.  Row r holds its 8 16B-granules permuted by
    // g_phys = g_log ^ (r&7); lane needs k = kk*64 + h*32 + [0,32) of its row
    // = logical granules {kk*4+2h, +1}.  (r&7 == l&7 for all our rows.)
    int rowA[4], rowB[2], xg[2][2];
    #pragma unroll
    for (int rb = 0; rb < 4; ++rb) rowA[rb] = (wr * 128 + rb * 32 + l31) * BK;
    #pragma unroll
    for (int cb = 0; cb < 2; ++cb) rowB[cb] = (wc * 64 + cb * 32 + l31) * BK;
    #pragma unroll
    for (int kk = 0; kk < 2; ++kk) {
        xg[kk][0] = ((kk * 4 + h * 2)     ^ swz) * 16;
        xg[kk][1] = ((kk * 4 + h * 2 + 1) ^ swz) * 16;
    }

    f32x16 acc[4][2];
    #pragma unroll
    for (int i = 0; i < 4; ++i)
        #pragma unroll
        for (int j = 0; j < 2; ++j)
            acc[i][j] = (f32x16)(0.0f);

    // Prologue: stage K-tile 0 into slot 0 (8 loads/thread).
    stage_tile(arow, &As[0][0], tid);
    stage_tile(bcol, &Bs[0][0], tid);

    for (int kt = 0; kt < NKT; ++kt) {
        const int cur = kt & 1;
        if (kt + 1 < NKT) {
            stage_tile(arow + (kt + 1) * BK, &As[cur ^ 1][0], tid);
            stage_tile(bcol + (kt + 1) * BK, &Bs[cur ^ 1][0], tid);
            asm volatile("s_waitcnt vmcnt(8)" ::: "memory");   // tile kt landed
        } else {
            asm volatile("s_waitcnt vmcnt(0)" ::: "memory");
        }
        BAR;

        const unsigned char* as = &As[cur][0];
        const unsigned char* bs = &Bs[cur][0];
        #pragma unroll
        for (int kk = 0; kk < 2; ++kk) {
            i32x8 afr[4], bfr[2];
            #pragma unroll
            for (int rb = 0; rb < 4; ++rb) {
                const i32x4 p0 = *reinterpret_cast<const i32x4*>(&as[rowA[rb] + xg[kk][0]]);
                const i32x4 p1 = *reinterpret_cast<const i32x4*>(&as[rowA[rb] + xg[kk][1]]);
                i32x8 r; r[0]=p0[0]; r[1]=p0[1]; r[2]=p0[2]; r[3]=p0[3];
                         r[4]=p1[0]; r[5]=p1[1]; r[6]=p1[2]; r[7]=p1[3];
                afr[rb] = r;
            }
            #pragma unroll
            for (int cb = 0; cb < 2; ++cb) {
                const i32x4 p0 = *reinterpret_cast<const i32x4*>(&bs[rowB[cb] + xg[kk][0]]);
                const i32x4 p1 = *reinterpret_cast<const i32x4*>(&bs[rowB[cb] + xg[kk][1]]);
                i32x8 r; r[0]=p0[0]; r[1]=p0[1]; r[2]=p0[2]; r[3]=p0[3];
                         r[4]=p1[0]; r[5]=p1[1]; r[6]=p1[2]; r[7]=p1[3];
                bfr[cb] = r;
            }
            __builtin_amdgcn_s_setprio(1);
            #pragma unroll
            for (int rb = 0; rb < 4; ++rb)
                #pragma unroll
                for (int cb = 0; cb < 2; ++cb)
                    acc[rb][cb] = __builtin_amdgcn_mfma_scale_f32_32x32x64_f8f6f4(
                        afr[rb], bfr[cb], acc[rb][cb],
                        0, 0,                 // cbsz = fp8(e4m3), blgp = fp8(e4m3)
                        0, SCALE1,            // opsel_a, scale_a = 1.0
                        0, SCALE1);           // opsel_b, scale_b = 1.0
            __builtin_amdgcn_s_setprio(0);
        }
        BAR;   // all reads of slot cur done before next iter overwrites it
    }

    // Fused epilogue (column-side only; full grid covers both (i,j),(j,i)).
    // 32x32 C/D layout: col = l&31, row = (reg&3) + 8*(reg>>2) + 4*(l>>5)
    // [m74/m101; shape-determined, dtype-independent].  p = acc/256.
    int jc[2], tj[2];
    #pragma unroll
    for (int cb = 0; cb < 2; ++cb) {
        jc[cb] = colbase + wc * 64 + cb * 32 + l31;
        tj[cb] = tgt[jc[cb]];
    }
    float denc[2] = {0.f, 0.f};
    float posc[2] = {0.f, 0.f};

    #pragma unroll
    for (int rb = 0; rb < 4; ++rb) {
        #pragma unroll
        for (int q4 = 0; q4 < 4; ++q4) {
            const int ribase = rowbase + wr * 128 + rb * 32 + q4 * 8 + h * 4;
            const int4 tiv = *reinterpret_cast<const int4*>(&tgt[ribase]);
            const int tia[4] = {tiv.x, tiv.y, tiv.z, tiv.w};
            #pragma unroll
            for (int j = 0; j < 4; ++j) {
                const int gi = ribase + j;
                const int ti = tia[j];
                #pragma unroll
                for (int cb = 0; cb < 2; ++cb) {
                    const float s  = acc[rb][cb][q4 * 4 + j] * INV_S2;
                    const float pc = fmaxf(s, 1e-10f);
                    const float e  = __expf(TEMP_INV * pc);
                    if (ti != tj[cb]) {
                        denc[cb] += e;
                    } else if (gi != jc[cb]) {
                        posc[cb] += pc;
                    }
                }
            }
        }
    }

    // Lanes sharing a column differ only in bit 5.
    #pragma unroll
    for (int cb = 0; cb < 2; ++cb) {
        denc[cb] += __shfl_xor(denc[cb], 32, 64);
        posc[cb] += __shfl_xor(posc[cb], 32, 64);
        if (l < 32) {
            atomicAdd(&denw[jc[cb]], denc[cb]);
            atomicAdd(&posw[jc[cb]], posc[cb]);
        }
    }
}

// Single-block finalize: LDS class histogram + per-column loss + direct store.
__global__ __launch_bounds__(1024) void finalize_k(const float* __restrict__ posw,
                                                   const float* __restrict__ denw,
                                                   const int* __restrict__ tgt,
                                                   float* __restrict__ out) {
    __shared__ int hist[128];
    __shared__ float red[16];
    const int tid = threadIdx.x;
    if (tid < 128) hist[tid] = 0;
    __syncthreads();
    const int4 t4 = reinterpret_cast<const int4*>(tgt)[tid];   // 4 targets/thread
    atomicAdd(&hist[t4.x], 1);
    atomicAdd(&hist[t4.y], 1);
    atomicAdd(&hist[t4.z], 1);
    atomicAdd(&hist[t4.w], 1);
    __syncthreads();
    const int ta[4] = {t4.x, t4.y, t4.z, t4.w};
    float v = 0.0f;
    #pragma unroll
    for (int q = 0; q < 4; ++q) {
        const int j = tid * 4 + q;
        const float d = fmaxf(denw[j], 1e-10f);
        const float c = (float)(hist[ta[q]] - 1);
        v += TEMP_INV * posw[j] - c * __logf(d);
    }
    #pragma unroll
    for (int off = 32; off; off >>= 1) v += __shfl_xor(v, off, 64);
    if ((tid & 63) == 0) red[tid >> 6] = v;
    __syncthreads();
    if (tid == 0) {
        float s = 0.0f;
        #pragma unroll
        for (int i = 0; i < 16; ++i) s += red[i];
        out[0] = -s * (1.0f / 4096.0f);
    }
}

extern "C" void kernel_launch(void* const* d_in, const int* in_sizes, int n_in,
                              void* d_out, int out_size, void* d_ws, size_t ws_size,
                              hipStream_t stream) {
    const float* pred = (const float*)d_in[0];
    const int*   tgt  = (const int*)d_in[1];
    float* out = (float*)d_out;

    unsigned char* xn = (unsigned char*)d_ws;                        // 4 MB fp8
    float* posw = (float*)((char*)d_ws + (size_t)NROWS * DIM);
    float* denw = posw + NROWS;

    normalize_k<<<NROWS, 256, 0, stream>>>(pred, xn, posw, denw);

    fused_gram<<<NTB * NTB, 512, 0, stream>>>(xn, tgt, posw, denw);  // 256 blocks

    finalize_k<<<1, 1024, 0, stream>>>(posw, denw, tgt, out);
}

// Round 12
// 43.995 us; speedup vs baseline: 3.2348x; 3.2348x over previous
//
#include <hip/hip_runtime.h>
#include <hip/hip_bf16.h>

#define NROWS 4096
#define DIM   1024           // K elements; 1024 B/row in fp8
#define BT    256            // tile edge (256x256 per block)
#define BK    128            // K-step (128 B in fp8)
#define NKT   (DIM / BK)     // 8 K-steps
#define NTB   (NROWS / BT)   // 16 tile-blocks per edge
#define TEMP_INV 10.0f
#define INV_S2 0.00390625f   // 1/256 (fp8 stored as 16*x)

typedef float f32x4  __attribute__((ext_vector_type(4)));
typedef long  longx2 __attribute__((ext_vector_type(2)));   // 16B = 2 fp8x8

__device__ __forceinline__ void gload16(const void* g, void* l) {
    __builtin_amdgcn_global_load_lds(
        (const __attribute__((address_space(1))) void*)g,
        (__attribute__((address_space(3))) void*)l, 16, 0, 0);
}

// Stage one 256x128 fp8 K-tile (32 KB) into LDS, 4 x gload16 per thread
// (512 thr).  Proven 2.6us/64KB-step staging (R4/R9).  Linear LDS dest
// (m104); granule swizzle kg = (p&7)^(r&7) pre-applied on the global source.
__device__ __forceinline__ void stage_tile(const unsigned char* __restrict__ src,
                                           unsigned char* lds, int tid) {
    #pragma unroll
    for (int c = 0; c < 4; ++c) {
        const int p  = c * 512 + tid;        // granule 0..2047
        const int r  = p >> 3;               // tile row 0..255
        const int kg = (p & 7) ^ (r & 7);    // logical chunk held at p
        gload16(src + (size_t)r * DIM + kg * 16, lds + p * 16);
    }
}

// Row-normalize fp32 -> fp8 e4m3 scaled by 16, written K-PERMUTED:
// within each 128-k block, k = ks*32 + q*8 + j  ->  byte pos = q*32 + ks*8 + j
// (bijective bit shuffle).  Gram is k-permutation invariant (both operands
// share the layout); this makes each lane's fragments for MFMA slices
// {2r,2r+1} CONTIGUOUS 16B in LDS -> single ds_read_b128 (R4's proven
// conflict-free pattern) instead of R9's 48 ds_read_b64.
__global__ __launch_bounds__(256) void normalize_k(const float* __restrict__ pred,
                                                   unsigned char* __restrict__ xn,
                                                   float* __restrict__ posw,
                                                   float* __restrict__ denw) {
    const int row = blockIdx.x;
    const int tid = threadIdx.x;
    const float4 v = reinterpret_cast<const float4*>(pred + (size_t)row * DIM)[tid];
    float ss = v.x * v.x + v.y * v.y + v.z * v.z + v.w * v.w;
    #pragma unroll
    for (int off = 32; off; off >>= 1) ss += __shfl_xor(ss, off, 64);
    __shared__ float red[4];
    if ((tid & 63) == 0) red[tid >> 6] = ss;
    __syncthreads();
    const float tot = red[0] + red[1] + red[2] + red[3];
    const float scale = 16.0f / fmaxf(sqrtf(tot), 1e-8f);
    int pk = __builtin_amdgcn_cvt_pk_fp8_f32(v.x * scale, v.y * scale, 0, false);
    pk     = __builtin_amdgcn_cvt_pk_fp8_f32(v.z * scale, v.w * scale, pk, true);
    // This thread's 4 bytes are k = tid*4 + [0,4): ks = (tid&31)>>3,
    // q = ((tid&31)>>1)&3, j_base = (tid&1)*4.  int index = q*8 + ks*2 + (tid&1).
    const int t5 = tid & 31;
    const int widx = (tid >> 5) * 32 + ((t5 >> 1) & 3) * 8 + (t5 >> 3) * 2 + (t5 & 1);
    reinterpret_cast<int*>(xn)[row * (DIM / 4) + widx] = pk;
    if (tid == 0) { posw[row] = 0.0f; denw[row] = 0.0f; }
}

#define BAR asm volatile("s_barrier" ::: "memory")

// Fused Gram-GEMM + contrastive epilogue.  Full 16x16 grid (256 blocks,
// 1/CU), 8 waves (2M x 4N), per-wave output 128x64, 16x16x32 fp8 MFMA.
// R4/R9's counted-vmcnt staging; k-permuted layout gives 24 conflict-free
// ds_read_b128 per wave-step (each feeding TWO MFMA k-slices).
__global__ __launch_bounds__(512, 2) void fused_gram(
        const unsigned char* __restrict__ xn, const int* __restrict__ tgt,
        float* __restrict__ posw, float* __restrict__ denw) {
    __shared__ unsigned char As[2][BT * BK];   // 2 x 32 KB
    __shared__ unsigned char Bs[2][BT * BK];   // 2 x 32 KB  (128 KB total)

    const int bi = blockIdx.x >> 4;
    const int bj = blockIdx.x & 15;
    const int rowbase = bi * BT;
    const int colbase = bj * BT;

    const int tid = threadIdx.x;
    const int w   = tid >> 6;
    const int l   = tid & 63;
    const int wr  = w >> 2;      // 0..1  (row half: 128 rows)
    const int wc  = w & 3;       // 0..3  (col quarter: 64 cols)
    const int l15 = l & 15;
    const int kgl = l >> 4;      // q = 0..3

    const unsigned char* arow = xn + (size_t)rowbase * DIM;
    const unsigned char* bcol = xn + (size_t)colbase * DIM;

    // Per-lane LDS offsets.  Logical chunk for read r (slices 2r,2r+1) is
    // q*2 + r; physical chunk = logical ^ (row&7); row&7 == l15&7 here.
    int rowA[8], rowB[4], xr[2];
    #pragma unroll
    for (int fi = 0; fi < 8; ++fi) rowA[fi] = (wr * 128 + fi * 16 + l15) * BK;
    #pragma unroll
    for (int fj = 0; fj < 4; ++fj) rowB[fj] = (wc * 64 + fj * 16 + l15) * BK;
    #pragma unroll
    for (int r = 0; r < 2; ++r) xr[r] = ((kgl * 2 + r) ^ (l15 & 7)) * 16;

    f32x4 acc[8][4];
    #pragma unroll
    for (int i = 0; i < 8; ++i)
        #pragma unroll
        for (int j = 0; j < 4; ++j)
            acc[i][j] = (f32x4){0.f, 0.f, 0.f, 0.f};

    // Prologue: stage K-tile 0 into slot 0 (8 loads/thread).
    stage_tile(arow, &As[0][0], tid);
    stage_tile(bcol, &Bs[0][0], tid);

    for (int kt = 0; kt < NKT; ++kt) {
        const int cur = kt & 1;
        if (kt + 1 < NKT) {
            stage_tile(arow + (kt + 1) * BK, &As[cur ^ 1][0], tid);
            stage_tile(bcol + (kt + 1) * BK, &Bs[cur ^ 1][0], tid);
            asm volatile("s_waitcnt vmcnt(8)" ::: "memory");   // tile kt landed
        } else {
            asm volatile("s_waitcnt vmcnt(0)" ::: "memory");
        }
        BAR;

        const unsigned char* as = &As[cur][0];
        const unsigned char* bs = &Bs[cur][0];
        #pragma unroll
        for (int r = 0; r < 2; ++r) {
            longx2 a[8], b[4];
            #pragma unroll
            for (int fi = 0; fi < 8; ++fi)
                a[fi] = *reinterpret_cast<const longx2*>(&as[rowA[fi] + xr[r]]);
            #pragma unroll
            for (int fj = 0; fj < 4; ++fj)
                b[fj] = *reinterpret_cast<const longx2*>(&bs[rowB[fj] + xr[r]]);
            __builtin_amdgcn_s_setprio(1);
            #pragma unroll
            for (int fi = 0; fi < 8; ++fi)
                #pragma unroll
                for (int fj = 0; fj < 4; ++fj)
                    acc[fi][fj] = __builtin_amdgcn_mfma_f32_16x16x32_fp8_fp8(
                        a[fi][0], b[fj][0], acc[fi][fj], 0, 0, 0);   // slice 2r
            #pragma unroll
            for (int fi = 0; fi < 8; ++fi)
                #pragma unroll
                for (int fj = 0; fj < 4; ++fj)
                    acc[fi][fj] = __builtin_amdgcn_mfma_f32_16x16x32_fp8_fp8(
                        a[fi][1], b[fj][1], acc[fi][fj], 0, 0, 0);   // slice 2r+1
            __builtin_amdgcn_s_setprio(0);
        }
        BAR;   // all reads of slot cur done before next iter overwrites it
    }

    // Fused epilogue (column-side only; full grid covers both (i,j),(j,i)).
    // C/D layout: col = lane&15, row = (lane>>4)*4 + q.  p = acc/256.
    int jc[4], tj[4];
    #pragma unroll
    for (int fj = 0; fj < 4; ++fj) {
        jc[fj] = colbase + wc * 64 + fj * 16 + l15;
        tj[fj] = tgt[jc[fj]];
    }
    float denc[4] = {0.f, 0.f, 0.f, 0.f};
    float posc[4] = {0.f, 0.f, 0.f, 0.f};

    #pragma unroll
    for (int fi = 0; fi < 8; ++fi) {
        const int ribase = rowbase + wr * 128 + fi * 16 + (l >> 4) * 4;
        const int4 tiv = *reinterpret_cast<const int4*>(&tgt[ribase]);
        const int tia[4] = {tiv.x, tiv.y, tiv.z, tiv.w};
        #pragma unroll
        for (int q = 0; q < 4; ++q) {
            const int gi = ribase + q;
            const int ti = tia[q];
            #pragma unroll
            for (int fj = 0; fj < 4; ++fj) {
                const float s  = acc[fi][fj][q] * INV_S2;
                const float pc = fmaxf(s, 1e-10f);
                const float e  = __expf(TEMP_INV * pc);
                if (ti != tj[fj]) {
                    denc[fj] += e;
                } else if (gi != jc[fj]) {
                    posc[fj] += pc;
                }
            }
        }
    }

    // Lanes sharing a column differ in bits 4-5.
    #pragma unroll
    for (int fj = 0; fj < 4; ++fj) {
        #pragma unroll
        for (int off = 16; off < 64; off <<= 1) {
            denc[fj] += __shfl_xor(denc[fj], off, 64);
            posc[fj] += __shfl_xor(posc[fj], off, 64);
        }
        if (l < 16) {
            atomicAdd(&denw[jc[fj]], denc[fj]);
            atomicAdd(&posw[jc[fj]], posc[fj]);
        }
    }
}

// Single-block finalize: LDS class histogram + per-column loss + direct store.
__global__ __launch_bounds__(1024) void finalize_k(const float* __restrict__ posw,
                                                   const float* __restrict__ denw,
                                                   const int* __restrict__ tgt,
                                                   float* __restrict__ out) {
    __shared__ int hist[128];
    __shared__ float red[16];
    const int tid = threadIdx.x;
    if (tid < 128) hist[tid] = 0;
    __syncthreads();
    const int4 t4 = reinterpret_cast<const int4*>(tgt)[tid];   // 4 targets/thread
    atomicAdd(&hist[t4.x], 1);
    atomicAdd(&hist[t4.y], 1);
    atomicAdd(&hist[t4.z], 1);
    atomicAdd(&hist[t4.w], 1);
    __syncthreads();
    const int ta[4] = {t4.x, t4.y, t4.z, t4.w};
    float v = 0.0f;
    #pragma unroll
    for (int q = 0; q < 4; ++q) {
        const int j = tid * 4 + q;
        const float d = fmaxf(denw[j], 1e-10f);
        const float c = (float)(hist[ta[q]] - 1);
        v += TEMP_INV * posw[j] - c * __logf(d);
    }
    #pragma unroll
    for (int off = 32; off; off >>= 1) v += __shfl_xor(v, off, 64);
    if ((tid & 63) == 0) red[tid >> 6] = v;
    __syncthreads();
    if (tid == 0) {
        float s = 0.0f;
        #pragma unroll
        for (int i = 0; i < 16; ++i) s += red[i];
        out[0] = -s * (1.0f / 4096.0f);
    }
}

extern "C" void kernel_launch(void* const* d_in, const int* in_sizes, int n_in,
                              void* d_out, int out_size, void* d_ws, size_t ws_size,
                              hipStream_t stream) {
    const float* pred = (const float*)d_in[0];
    const int*   tgt  = (const int*)d_in[1];
    float* out = (float*)d_out;

    unsigned char* xn = (unsigned char*)d_ws;                        // 4 MB fp8
    float* posw = (float*)((char*)d_ws + (size_t)NROWS * DIM);
    float* denw = posw + NROWS;

    normalize_k<<<NROWS, 256, 0, stream>>>(pred, xn, posw, denw);

    fused_gram<<<NTB * NTB, 512, 0, stream>>>(xn, tgt, posw, denw);  // 256 blocks

    finalize_k<<<1, 1024, 0, stream>>>(posw, denw, tgt, out);
}